// Round 3
// baseline (46707.220 us; speedup 1.0000x reference)
//
#include <hip/hip_runtime.h>
#include <hip/hip_bf16.h>
#include <stdint.h>

#define NWG 256
typedef unsigned long long u64;

typedef __attribute__((ext_vector_type(8))) short bf16x8;
typedef __attribute__((ext_vector_type(4))) float f32x4;

__device__ __forceinline__ short f2bf(float f) {
    unsigned u = __float_as_uint(f);
    unsigned r = (u + 0x7fffu + ((u >> 16) & 1u)) >> 16;
    return (short)r;
}

__device__ __forceinline__ void gload16(const void* g, void* l) {
    __builtin_amdgcn_global_load_lds(
        (const __attribute__((address_space(1))) void*)g,
        (__attribute__((address_space(3))) void*)l, 16, 0, 0);
}

__device__ __forceinline__ u64 ald(const u64* p) {
    return __hip_atomic_load(p, __ATOMIC_RELAXED, __HIP_MEMORY_SCOPE_AGENT);
}
__device__ __forceinline__ void ast(u64* p, u64 v) {
    __hip_atomic_store(p, v, __ATOMIC_RELAXED, __HIP_MEMORY_SCOPE_AGENT);
}
__device__ __forceinline__ u64 pack(unsigned tag, float f) {
    return ((u64)tag << 32) | (u64)(unsigned)__float_as_uint(f);
}

// ---------------- P1: misc prep (grid-stride) ----------------
__global__ void prep_all(const int* __restrict__ x, const int* __restrict__ Vg, const int* __restrict__ Jg,
                         const float* __restrict__ emb, const float* __restrict__ embV, const float* __restrict__ embJ,
                         const float* __restrict__ Wih_e,
                         const float* __restrict__ Wih_d, const float* __restrict__ Whh_d,
                         float* __restrict__ out,
                         short* __restrict__ Abf, short* __restrict__ Wbf,
                         float* __restrict__ wsum,
                         u64* __restrict__ bufE, u64* __restrict__ bufD)
{
    const size_t i0 = (size_t)blockIdx.x * blockDim.x + threadIdx.x;
    const size_t str = (size_t)gridDim.x * blockDim.x;
    for (size_t i = i0; i < (size_t)4096 * 1024; i += str) {
        int t = (int)(i >> 10), j = (int)(i & 1023);
        float v = emb[(size_t)x[t] * 1024 + j];
        out[4195328 + i] = v;
        Abf[i] = f2bf(v);
    }
    for (size_t i = i0; i < (size_t)8192 * 1024; i += str) Wbf[i] = f2bf(Wih_e[i]);
    for (size_t i = i0; i < (size_t)4096 * 1024; i += str) wsum[i] = Wih_d[i] + Whh_d[i];
    for (size_t i = i0; i < 1024; i += str) {
        out[1024 + i] = emb[1 * 1024 + i];                        // recon row 0    = emb[B_IDX]
        out[1024 + (size_t)4095 * 1024 + i] = emb[23 * 1024 + i]; // recon row 4095 = emb[X_IDX]
    }
    // encoder h buffers [3][2048]: zeros (h_0 = 0 with tag 0; others tag 0 but polled for tags 1,2)
    for (size_t i = i0; i < 6144; i += str) bufE[i] = 0ull;
    // decoder h buffers [3][1024]: buf0 = latent_cat slots; buf1/2 zeros (tag 0, polled for 1,2)
    for (size_t i = i0; i < 3072; i += str) {
        u64 v = 0ull;
        if (i < 1024) {
            if (i < 128)      v = pack(0u, embV[(size_t)Vg[0] * 128 + i]);
            else if (i < 896) v = 0xFFFFFFFF00000000ull;   // latent sentinel (tag != 0)
            else              v = pack(0u, embJ[(size_t)Jg[0] * 128 + (i - 896)]);
        }
        bufD[i] = v;
    }
    for (size_t i = i0; i < 128; i += str) {
        out[i]       = embV[(size_t)Vg[0] * 128 + i];
        out[896 + i] = embJ[(size_t)Jg[0] * 128 + i];
    }
}

// ---------------- P2: pg = W_ih_dec @ prev0 + b_dec ----------------
__global__ void prep_pg(const float* __restrict__ Wih_d, const float* __restrict__ emb,
                        const float* __restrict__ bih_d, const float* __restrict__ bhh_d,
                        float* __restrict__ pg)
{
    const int lane = threadIdx.x & 63, wv = threadIdx.x >> 6;
    const float* prev0 = emb + 23 * 1024;
    for (int rr = 0; rr < 16; rr++) {
        int row = blockIdx.x * 64 + wv * 16 + rr;
        float s = 0.f;
        #pragma unroll
        for (int q = 0; q < 16; q++) {
            int k = lane + q * 64;
            s += Wih_d[(size_t)row * 1024 + k] * prev0[k];
        }
        for (int o = 32; o; o >>= 1) s += __shfl_xor(s, o, 64);
        if (lane == 0) pg[row] = s + bih_d[row] + bhh_d[row];
    }
}

// ---------------- P3: Gxt = embedded @ W_ih_enc^T + (bih+bhh), TRANSPOSED to [t][h][gate] ----------------
__launch_bounds__(256, 2)
__global__ void gemm_xgates(const short* __restrict__ A,   // [4096][1024] bf16 bits
                            const short* __restrict__ B,   // [8192][1024] bf16 bits
                            const float* __restrict__ bih, const float* __restrict__ bhh,
                            float* __restrict__ C)         // [4096][2048][4]  (h-major, gate minor)
{
    __shared__ short lA[128 * 32];
    __shared__ short lB[128 * 32];
    const int bid = blockIdx.x;
    const int mb = bid >> 6;
    const int nb = bid & 63;
    const int tid = threadIdx.x, lane = tid & 63, wv = tid >> 6;
    const int wr = wv >> 1, wc = wv & 1;
    const int Mbase = mb * 128, Nbase = nb * 128;
    f32x4 acc[4][4] = {};

    for (int kt = 0; kt < 32; kt++) {
        __syncthreads();
        const int k0b = kt * 64;
        #pragma unroll
        for (int c = 0; c < 2; c++) {
            int f = tid * 16 + c * 4096;
            int row = f >> 6, kb = f & 63;
            const char* ga = (const char*)A + (size_t)(Mbase + row) * 2048 + k0b + kb;
            const char* gb = (const char*)B + (size_t)(Nbase + row) * 2048 + k0b + kb;
            gload16(ga, (char*)lA + wv * 1024 + c * 4096);
            gload16(gb, (char*)lB + wv * 1024 + c * 4096);
        }
        asm volatile("s_waitcnt vmcnt(0)" ::: "memory");
        __syncthreads();
        bf16x8 af[4], bf[4];
        #pragma unroll
        for (int i = 0; i < 4; i++) {
            af[i] = *(const bf16x8*)&lA[(wr * 64 + i * 16 + (lane & 15)) * 32 + (lane >> 4) * 8];
            bf[i] = *(const bf16x8*)&lB[(wc * 64 + i * 16 + (lane & 15)) * 32 + (lane >> 4) * 8];
        }
        #pragma unroll
        for (int i = 0; i < 4; i++)
            #pragma unroll
            for (int j = 0; j < 4; j++)
                acc[i][j] = __builtin_amdgcn_mfma_f32_16x16x32_bf16(af[i], bf[j], acc[i][j], 0, 0, 0);
    }
    #pragma unroll
    for (int i = 0; i < 4; i++) {
        #pragma unroll
        for (int j = 0; j < 4; j++) {
            int col = Nbase + wc * 64 + j * 16 + (lane & 15);   // gate-row index in [0,8192)
            float bv = bih[col] + bhh[col];
            int dst = ((col & 2047) << 2) | (col >> 11);         // h*4 + gate
            #pragma unroll
            for (int r = 0; r < 4; r++) {
                int row = Mbase + wr * 64 + i * 16 + (lane >> 4) * 4 + r;
                C[(size_t)row * 8192 + dst] = acc[i][j][r] + bv;
            }
        }
    }
}

// ---------------- P4: persistent sequential LSTM (in-wave gates, 1 sync/step) ----------------
__launch_bounds__(512, 2)
__global__ void rnn_seq(const float* __restrict__ Whh_e,   // [8192][2048]
                        const float* __restrict__ Wls,     // [768][2048]
                        const float* __restrict__ bls,     // [768]
                        const float* __restrict__ Whh_d,   // [4096][1024]
                        const float* __restrict__ Gxt,     // [4096][2048][4]
                        const float* __restrict__ wsum,    // [4096][1024]
                        const float* __restrict__ bih_d, const float* __restrict__ bhh_d,
                        const float* __restrict__ pg,      // [4096]
                        u64* __restrict__ bufE,            // [3][2048] tagged h (enc)
                        u64* __restrict__ bufD,            // [3][1024] tagged h (dec)
                        float* __restrict__ out)
{
    const int w = blockIdx.x;
    const int tid = threadIdx.x;
    const int lane = tid & 63, wv = tid >> 6;
    __shared__ float hl[2][2048];

    // ---- encoder weights: wave wv owns h-index 8w+wv, all 4 gate rows.
    //      lane owns k = 4*lane + 256*jj + c  (matches float4 LDS reads)
    const int hidxE = 8 * w + wv;
    float4 we[4][8];
    #pragma unroll
    for (int g = 0; g < 4; g++) {
        const float* src = Whh_e + (size_t)(g * 2048 + hidxE) * 2048 + 4 * lane;
        #pragma unroll
        for (int jj = 0; jj < 8; jj++) we[g][jj] = *(const float4*)(src + 256 * jj);
    }
    float c = 0.f;   // cell state, replicated across lanes

    // prologue: x-gate terms for t=0 (lane g<4 holds gate g)
    float gx = 0.f;
    if (lane < 4) gx = Gxt[(size_t)hidxE * 4 + lane];

    // ================= encoder: 4096 steps =================
    #pragma unroll 1
    for (int t = 0; t < 4096; t++) {
        // poll own chunk: lane owns 4 consecutive tagged values
        const unsigned tg = (unsigned)t;
        const u64* p = bufE + (size_t)(t % 3) * 2048 + wv * 256 + 4 * lane;
        u64 a0 = ald(p), a1 = ald(p + 1), a2 = ald(p + 2), a3 = ald(p + 3);
        for (;;) {
            bool ok = ((unsigned)(a0 >> 32) == tg) & ((unsigned)(a1 >> 32) == tg)
                    & ((unsigned)(a2 >> 32) == tg) & ((unsigned)(a3 >> 32) == tg);
            if (__builtin_expect(__all(ok), 1)) break;
            a0 = ald(p); a1 = ald(p + 1); a2 = ald(p + 2); a3 = ald(p + 3);
        }
        float4 hv = { __uint_as_float((unsigned)a0), __uint_as_float((unsigned)a1),
                      __uint_as_float((unsigned)a2), __uint_as_float((unsigned)a3) };
        *(float4*)&hl[t & 1][wv * 256 + 4 * lane] = hv;
        __syncthreads();

        // prefetch next step's x-gates (consumed next iteration; hides HBM latency)
        float gx_next = 0.f;
        if (lane < 4 && t < 4095) gx_next = Gxt[(size_t)(t + 1) * 8192 + hidxE * 4 + lane];

        float s0 = 0.f, s1 = 0.f, s2 = 0.f, s3 = 0.f;
        const float4* hp = (const float4*)hl[t & 1];
        #pragma unroll
        for (int jj = 0; jj < 8; jj++) {
            float4 h4 = hp[lane + 64 * jj];
            s0 += we[0][jj].x * h4.x; s0 += we[0][jj].y * h4.y; s0 += we[0][jj].z * h4.z; s0 += we[0][jj].w * h4.w;
            s1 += we[1][jj].x * h4.x; s1 += we[1][jj].y * h4.y; s1 += we[1][jj].z * h4.z; s1 += we[1][jj].w * h4.w;
            s2 += we[2][jj].x * h4.x; s2 += we[2][jj].y * h4.y; s2 += we[2][jj].z * h4.z; s2 += we[2][jj].w * h4.w;
            s3 += we[3][jj].x * h4.x; s3 += we[3][jj].y * h4.y; s3 += we[3][jj].z * h4.z; s3 += we[3][jj].w * h4.w;
        }
        #pragma unroll
        for (int o = 32; o; o >>= 1) {
            s0 += __shfl_xor(s0, o, 64); s1 += __shfl_xor(s1, o, 64);
            s2 += __shfl_xor(s2, o, 64); s3 += __shfl_xor(s3, o, 64);
        }
        float gi = s0 + __shfl(gx, 0, 64);
        float gf = s1 + __shfl(gx, 1, 64);
        float gg = s2 + __shfl(gx, 2, 64);
        float go = s3 + __shfl(gx, 3, 64);
        float ig = 1.f / (1.f + expf(-gi));
        float fg = 1.f / (1.f + expf(-gf));
        float og = 1.f / (1.f + expf(-go));
        c = fg * c + ig * tanhf(gg);
        float hn = og * tanhf(c);
        if (lane == 0) ast(&bufE[(size_t)((t + 1) % 3) * 2048 + hidxE], pack(tg + 1, hn));
        gx = gx_next;
    }

    // ================= latent: 3 rows per WG (h_4096 has tag 4096, in bufE[4096%3==1]) =================
    {
        const unsigned tg = 4096u;
        const u64* p = bufE + (size_t)2048 + wv * 256 + 4 * lane;
        u64 a0 = ald(p), a1 = ald(p + 1), a2 = ald(p + 2), a3 = ald(p + 3);
        for (;;) {
            bool ok = ((unsigned)(a0 >> 32) == tg) & ((unsigned)(a1 >> 32) == tg)
                    & ((unsigned)(a2 >> 32) == tg) & ((unsigned)(a3 >> 32) == tg);
            if (__builtin_expect(__all(ok), 1)) break;
            a0 = ald(p); a1 = ald(p + 1); a2 = ald(p + 2); a3 = ald(p + 3);
        }
        float4 hv = { __uint_as_float((unsigned)a0), __uint_as_float((unsigned)a1),
                      __uint_as_float((unsigned)a2), __uint_as_float((unsigned)a3) };
        *(float4*)&hl[0][wv * 256 + 4 * lane] = hv;
        __syncthreads();

        if (wv < 3) {
            int row = 3 * w + wv;
            const float* wr = Wls + (size_t)row * 2048;
            float s = 0.f;
            #pragma unroll
            for (int q = 0; q < 32; q++) s += wr[lane + 64 * q] * hl[0][lane + 64 * q];
            for (int o = 32; o; o >>= 1) s += __shfl_xor(s, o, 64);
            if (lane == 0) {
                float lv = tanhf(s + bls[row]);
                out[128 + row] = lv;
                ast(&bufD[128 + row], pack(0u, lv));
            }
        }
        __syncthreads();   // hl[0] reads done before decoder s=1 re-stages hl[0]
    }

    // ---- decoder weights: wave wv<4 owns h-index 4w+wv, all 4 gate rows (k = 4*lane+256*jj+c)
    const int hidxD = 4 * w + (wv & 3);
    float4 wd[4][4];
    float bdv = 0.f, pgv = 0.f, cD = 0.f;
    if (wv < 4) {
        #pragma unroll
        for (int g = 0; g < 4; g++) {
            const float* src = wsum + (size_t)(g * 1024 + hidxD) * 1024 + 4 * lane;
            #pragma unroll
            for (int jj = 0; jj < 4; jj++) wd[g][jj] = *(const float4*)(src + 256 * jj);
        }
        if (lane < 4) {
            int R = lane * 1024 + hidxD;
            bdv = bih_d[R] + bhh_d[R];
            pgv = pg[R];
        }
        // c0 = latent_cat[hidxD]: poll tag 0 (all lanes, same address -> broadcast)
        const u64* pc = bufD + hidxD;
        u64 v;
        do { v = ald(pc); } while ((unsigned)(v >> 32) != 0u);
        cD = __uint_as_float((unsigned)v);
    }

    // ================= decoder: 4094 steps =================
    #pragma unroll 1
    for (int s = 1; s <= 4094; s++) {
        const unsigned tg = (unsigned)(s - 1);
        const u64* p = bufD + (size_t)((s - 1) % 3) * 1024 + wv * 128 + 2 * lane;
        u64 a0 = ald(p), a1 = ald(p + 1);
        for (;;) {
            bool ok = ((unsigned)(a0 >> 32) == tg) & ((unsigned)(a1 >> 32) == tg);
            if (__builtin_expect(__all(ok), 1)) break;
            a0 = ald(p); a1 = ald(p + 1);
        }
        float2 hv = { __uint_as_float((unsigned)a0), __uint_as_float((unsigned)a1) };
        *(float2*)&hl[(s - 1) & 1][wv * 128 + 2 * lane] = hv;
        __syncthreads();

        if (wv < 4) {
            float s0 = 0.f, s1 = 0.f, s2 = 0.f, s3 = 0.f;
            const float4* hp = (const float4*)hl[(s - 1) & 1];
            if (s == 1) {
                // first step uses W_hh_dec alone (input is emb[X], its term is in pg)
                #pragma unroll
                for (int g = 0; g < 4; g++) {
                    const float* srcw = Whh_d + (size_t)(g * 1024 + hidxD) * 1024 + 4 * lane;
                    float a = 0.f;
                    #pragma unroll
                    for (int jj = 0; jj < 4; jj++) {
                        float4 w4 = *(const float4*)(srcw + 256 * jj);
                        float4 h4 = hp[lane + 64 * jj];
                        a += w4.x * h4.x + w4.y * h4.y + w4.z * h4.z + w4.w * h4.w;
                    }
                    if (g == 0) s0 = a; else if (g == 1) s1 = a; else if (g == 2) s2 = a; else s3 = a;
                }
            } else {
                #pragma unroll
                for (int jj = 0; jj < 4; jj++) {
                    float4 h4 = hp[lane + 64 * jj];
                    s0 += wd[0][jj].x * h4.x; s0 += wd[0][jj].y * h4.y; s0 += wd[0][jj].z * h4.z; s0 += wd[0][jj].w * h4.w;
                    s1 += wd[1][jj].x * h4.x; s1 += wd[1][jj].y * h4.y; s1 += wd[1][jj].z * h4.z; s1 += wd[1][jj].w * h4.w;
                    s2 += wd[2][jj].x * h4.x; s2 += wd[2][jj].y * h4.y; s2 += wd[2][jj].z * h4.z; s2 += wd[2][jj].w * h4.w;
                    s3 += wd[3][jj].x * h4.x; s3 += wd[3][jj].y * h4.y; s3 += wd[3][jj].z * h4.z; s3 += wd[3][jj].w * h4.w;
                }
            }
            #pragma unroll
            for (int o = 32; o; o >>= 1) {
                s0 += __shfl_xor(s0, o, 64); s1 += __shfl_xor(s1, o, 64);
                s2 += __shfl_xor(s2, o, 64); s3 += __shfl_xor(s3, o, 64);
            }
            float bb = (s == 1) ? pgv : bdv;
            float gi = s0 + __shfl(bb, 0, 64);
            float gf = s1 + __shfl(bb, 1, 64);
            float gg = s2 + __shfl(bb, 2, 64);
            float go = s3 + __shfl(bb, 3, 64);
            float ig = 1.f / (1.f + expf(-gi));
            float fg = 1.f / (1.f + expf(-gf));
            float og = 1.f / (1.f + expf(-go));
            cD = fg * cD + ig * tanhf(gg);
            float hn = og * tanhf(cD);
            if (lane == 0) {
                out[1024 + (size_t)(4095 - s) * 1024 + hidxD] = hn;
                ast(&bufD[(size_t)(s % 3) * 1024 + hidxD], pack((unsigned)s, hn));
            }
        }
    }
}

// ---------------- host launcher ----------------
extern "C" void kernel_launch(void* const* d_in, const int* in_sizes, int n_in,
                              void* d_out, int out_size, void* d_ws, size_t ws_size,
                              hipStream_t stream)
{
    const int* x      = (const int*)d_in[0];
    const int* Vg     = (const int*)d_in[1];
    const int* Jg     = (const int*)d_in[2];
    const float* emb   = (const float*)d_in[4];
    const float* embV  = (const float*)d_in[5];
    const float* embJ  = (const float*)d_in[6];
    const float* Wih_e = (const float*)d_in[7];
    const float* Whh_e = (const float*)d_in[8];
    const float* bih_e = (const float*)d_in[9];
    const float* bhh_e = (const float*)d_in[10];
    const float* Wls   = (const float*)d_in[11];
    const float* bls   = (const float*)d_in[12];
    const float* Wih_d = (const float*)d_in[13];
    const float* Whh_d = (const float*)d_in[14];
    const float* bih_d = (const float*)d_in[15];
    const float* bhh_d = (const float*)d_in[16];
    float* out = (float*)d_out;

    char* ws = (char*)d_ws;
    u64*   bufE = (u64*)ws;                     // [3][2048]  -> 49152 B
    u64*   bufD = (u64*)(ws + 49152);           // [3][1024]  -> 24576 B
    float* pg   = (float*)(ws + 73728);         // [4096]     -> 16384 B
    short* Abf  = (short*)(ws + 90368);         // [4096*1024]
    short* Wbf  = (short*)(ws + 8478976);       // [8192*1024]
    float* wsum = (float*)(ws + 25256192);      // [4096*1024]
    float* Gxt  = (float*)(ws + 42033408);      // [4096][2048][4]  (total 176,251,136 B)

    prep_all<<<1024, 256, 0, stream>>>(x, Vg, Jg, emb, embV, embJ,
                                       Wih_e, Wih_d, Whh_d,
                                       out, Abf, Wbf, wsum, bufE, bufD);
    prep_pg<<<64, 256, 0, stream>>>(Wih_d, emb, bih_d, bhh_d, pg);
    gemm_xgates<<<2048, 256, 0, stream>>>(Abf, Wbf, bih_e, bhh_e, Gxt);

    void* args[] = { (void*)&Whh_e, (void*)&Wls, (void*)&bls, (void*)&Whh_d,
                     (void*)&Gxt, (void*)&wsum, (void*)&bih_d, (void*)&bhh_d, (void*)&pg,
                     (void*)&bufE, (void*)&bufD, (void*)&out };
    hipLaunchCooperativeKernel((const void*)rnn_seq, dim3(NWG), dim3(512), args, 0, stream);
}

// Round 4
// 24931.291 us; speedup vs baseline: 1.8734x; 1.8734x over previous
//
#include <hip/hip_runtime.h>
#include <hip/hip_bf16.h>
#include <stdint.h>

#define NWG 256
typedef unsigned long long u64;

typedef __attribute__((ext_vector_type(8))) short bf16x8;
typedef __attribute__((ext_vector_type(4))) float f32x4;

__device__ __forceinline__ short f2bf(float f) {
    unsigned u = __float_as_uint(f);
    unsigned r = (u + 0x7fffu + ((u >> 16) & 1u)) >> 16;
    return (short)r;
}

__device__ __forceinline__ void gload16(const void* g, void* l) {
    __builtin_amdgcn_global_load_lds(
        (const __attribute__((address_space(1))) void*)g,
        (__attribute__((address_space(3))) void*)l, 16, 0, 0);
}

__device__ __forceinline__ u64 ald(const u64* p) {
    return __hip_atomic_load(p, __ATOMIC_RELAXED, __HIP_MEMORY_SCOPE_AGENT);
}
__device__ __forceinline__ void ast(u64* p, u64 v) {
    __hip_atomic_store(p, v, __ATOMIC_RELAXED, __HIP_MEMORY_SCOPE_AGENT);
}
__device__ __forceinline__ u64 pack(unsigned tag, float f) {
    return ((u64)tag << 32) | (u64)(unsigned)__float_as_uint(f);
}

// ---------------- P1: misc prep (grid-stride) ----------------
__global__ void prep_all(const int* __restrict__ x, const int* __restrict__ Vg, const int* __restrict__ Jg,
                         const float* __restrict__ emb, const float* __restrict__ embV, const float* __restrict__ embJ,
                         const float* __restrict__ Wih_e,
                         const float* __restrict__ Wih_d, const float* __restrict__ Whh_d,
                         float* __restrict__ out,
                         short* __restrict__ Abf, short* __restrict__ Wbf,
                         float* __restrict__ wsum,
                         u64* __restrict__ bufE, u64* __restrict__ bufD)
{
    const size_t i0 = (size_t)blockIdx.x * blockDim.x + threadIdx.x;
    const size_t str = (size_t)gridDim.x * blockDim.x;
    for (size_t i = i0; i < (size_t)4096 * 1024; i += str) {
        int t = (int)(i >> 10), j = (int)(i & 1023);
        float v = emb[(size_t)x[t] * 1024 + j];
        out[4195328 + i] = v;
        Abf[i] = f2bf(v);
    }
    for (size_t i = i0; i < (size_t)8192 * 1024; i += str) Wbf[i] = f2bf(Wih_e[i]);
    for (size_t i = i0; i < (size_t)4096 * 1024; i += str) wsum[i] = Wih_d[i] + Whh_d[i];
    for (size_t i = i0; i < 1024; i += str) {
        out[1024 + i] = emb[1 * 1024 + i];                        // recon row 0    = emb[B_IDX]
        out[1024 + (size_t)4095 * 1024 + i] = emb[23 * 1024 + i]; // recon row 4095 = emb[X_IDX]
    }
    // encoder h buffers [3][2048]: zeros (h_0 = 0 with tag 0; bufs 1,2 polled for tags 1,2 -> safe)
    for (size_t i = i0; i < 6144; i += str) bufE[i] = 0ull;
    // decoder h buffers [3][1024]: buf0 = latent_cat slots; buf1/2 zeros (tag 0, polled for 1,2)
    for (size_t i = i0; i < 3072; i += str) {
        u64 v = 0ull;
        if (i < 1024) {
            if (i < 128)      v = pack(0u, embV[(size_t)Vg[0] * 128 + i]);
            else if (i < 896) v = 0xFFFFFFFF00000000ull;   // latent sentinel (tag != 0)
            else              v = pack(0u, embJ[(size_t)Jg[0] * 128 + (i - 896)]);
        }
        bufD[i] = v;
    }
    for (size_t i = i0; i < 128; i += str) {
        out[i]       = embV[(size_t)Vg[0] * 128 + i];
        out[896 + i] = embJ[(size_t)Jg[0] * 128 + i];
    }
}

// ---------------- P2: pg = W_ih_dec @ prev0 + b_dec ----------------
__global__ void prep_pg(const float* __restrict__ Wih_d, const float* __restrict__ emb,
                        const float* __restrict__ bih_d, const float* __restrict__ bhh_d,
                        float* __restrict__ pg)
{
    const int lane = threadIdx.x & 63, wv = threadIdx.x >> 6;
    const float* prev0 = emb + 23 * 1024;
    for (int rr = 0; rr < 16; rr++) {
        int row = blockIdx.x * 64 + wv * 16 + rr;
        float s = 0.f;
        #pragma unroll
        for (int q = 0; q < 16; q++) {
            int k = lane + q * 64;
            s += Wih_d[(size_t)row * 1024 + k] * prev0[k];
        }
        for (int o = 32; o; o >>= 1) s += __shfl_xor(s, o, 64);
        if (lane == 0) pg[row] = s + bih_d[row] + bhh_d[row];
    }
}

// ---------------- P3: Gx = embedded @ W_ih_enc^T + (bih+bhh) (bf16 MFMA) ----------------
__launch_bounds__(256, 2)
__global__ void gemm_xgates(const short* __restrict__ A,   // [4096][1024] bf16 bits
                            const short* __restrict__ B,   // [8192][1024] bf16 bits
                            const float* __restrict__ bih, const float* __restrict__ bhh,
                            float* __restrict__ C)         // [4096][8192]
{
    __shared__ short lA[128 * 32];
    __shared__ short lB[128 * 32];
    const int bid = blockIdx.x;
    const int mb = bid >> 6;
    const int nb = bid & 63;
    const int tid = threadIdx.x, lane = tid & 63, wv = tid >> 6;
    const int wr = wv >> 1, wc = wv & 1;
    const int Mbase = mb * 128, Nbase = nb * 128;
    f32x4 acc[4][4] = {};

    for (int kt = 0; kt < 32; kt++) {
        __syncthreads();
        const int k0b = kt * 64;
        #pragma unroll
        for (int c = 0; c < 2; c++) {
            int f = tid * 16 + c * 4096;
            int row = f >> 6, kb = f & 63;
            const char* ga = (const char*)A + (size_t)(Mbase + row) * 2048 + k0b + kb;
            const char* gb = (const char*)B + (size_t)(Nbase + row) * 2048 + k0b + kb;
            gload16(ga, (char*)lA + wv * 1024 + c * 4096);
            gload16(gb, (char*)lB + wv * 1024 + c * 4096);
        }
        asm volatile("s_waitcnt vmcnt(0)" ::: "memory");
        __syncthreads();
        bf16x8 af[4], bf[4];
        #pragma unroll
        for (int i = 0; i < 4; i++) {
            af[i] = *(const bf16x8*)&lA[(wr * 64 + i * 16 + (lane & 15)) * 32 + (lane >> 4) * 8];
            bf[i] = *(const bf16x8*)&lB[(wc * 64 + i * 16 + (lane & 15)) * 32 + (lane >> 4) * 8];
        }
        #pragma unroll
        for (int i = 0; i < 4; i++)
            #pragma unroll
            for (int j = 0; j < 4; j++)
                acc[i][j] = __builtin_amdgcn_mfma_f32_16x16x32_bf16(af[i], bf[j], acc[i][j], 0, 0, 0);
    }
    #pragma unroll
    for (int i = 0; i < 4; i++) {
        #pragma unroll
        for (int j = 0; j < 4; j++) {
            int col = Nbase + wc * 64 + j * 16 + (lane & 15);
            float bv = bih[col] + bhh[col];
            #pragma unroll
            for (int r = 0; r < 4; r++) {
                int row = Mbase + wr * 64 + i * 16 + (lane >> 4) * 4 + r;
                C[(size_t)row * 8192 + col] = acc[i][j][r] + bv;
            }
        }
    }
}

// ---------------- P4: persistent sequential LSTM (1024 thr/WG, registers guaranteed) ----------------
__launch_bounds__(1024, 4)
__global__ void rnn_seq(const float* __restrict__ Whh_e,   // [8192][2048]
                        const float* __restrict__ Wls,     // [768][2048]
                        const float* __restrict__ bls,     // [768]
                        const float* __restrict__ Whh_d,   // [4096][1024]
                        const float* __restrict__ Gx,      // [4096][8192]
                        const float* __restrict__ wsum,    // [4096][1024]
                        const float* __restrict__ bih_d, const float* __restrict__ bhh_d,
                        const float* __restrict__ pg,      // [4096]
                        u64* __restrict__ bufE,            // [3][2048] tagged h (enc)
                        u64* __restrict__ bufD,            // [3][1024] tagged h (dec)
                        float* __restrict__ out)
{
    const int w = blockIdx.x;
    const int tid = threadIdx.x;
    const int lane = tid & 63, wv = tid >> 6;       // 16 waves
    __shared__ float hl[2][2048];
    __shared__ float red[2][32];
    __shared__ float cst[8];

    // ---- encoder weights: wave wv owns gate-rows {2wv, 2wv+1} of this WG's 32 rows.
    //      Row r (0..31): gate = r>>3, h-slot = r&7 -> global row (r>>3)*2048 + 8w + (r&7).
    //      Lane owns k = lane + 64*j  (64 weight floats/lane -> stays in VGPRs).
    float we[64];
    #pragma unroll
    for (int rr = 0; rr < 2; rr++) {
        int r = wv * 2 + rr;
        const float* src = Whh_e + (size_t)((r >> 3) * 2048 + 8 * w + (r & 7)) * 2048 + lane;
        #pragma unroll
        for (int j = 0; j < 32; j++) we[rr * 32 + j] = src[64 * j];
    }
    if (tid < 8) cst[tid] = 0.f;
    const int grow = (tid >> 3) * 2048 + 8 * w + (tid & 7);   // valid for tid<32
    float gx = 0.f;
    if (tid < 32) gx = Gx[grow];                              // t=0 x-gates (+bias)
    __syncthreads();

    // ================= encoder: 4096 steps =================
    #pragma unroll 1
    for (int t = 0; t < 4096; t++) {
        // poll own chunk: wave covers u64 indices [wv*128, wv*128+128)
        const unsigned tg = (unsigned)t;
        const u64* p = bufE + (size_t)(t % 3) * 2048 + wv * 128 + 2 * lane;
        u64 a0 = ald(p), a1 = ald(p + 1);
        for (;;) {
            bool ok = ((unsigned)(a0 >> 32) == tg) & ((unsigned)(a1 >> 32) == tg);
            if (__builtin_expect(__all(ok), 1)) break;
            a0 = ald(p); a1 = ald(p + 1);
        }
        float2 hv = { __uint_as_float((unsigned)a0), __uint_as_float((unsigned)a1) };
        *(float2*)&hl[t & 1][wv * 128 + 2 * lane] = hv;
        __syncthreads();

        // prefetch next step's x-gates (consumed next iteration; hides HBM latency,
        // and keeps the poll loop free of in-order vmcnt dependence on HBM)
        float gx_next = 0.f;
        if (tid < 32 && t < 4095) gx_next = Gx[(size_t)(t + 1) * 8192 + grow];

        float s0 = 0.f, s1 = 0.f;
        const float* hp = hl[t & 1];
        #pragma unroll
        for (int j = 0; j < 32; j++) {
            float h = hp[lane + 64 * j];
            s0 += we[j] * h;
            s1 += we[32 + j] * h;
        }
        #pragma unroll
        for (int o = 32; o; o >>= 1) {
            s0 += __shfl_xor(s0, o, 64);
            s1 += __shfl_xor(s1, o, 64);
        }
        if (lane == 0) { red[t & 1][wv * 2] = s0; red[t & 1][wv * 2 + 1] = s1; }
        __syncthreads();

        if (tid < 32) {
            float g = red[t & 1][tid] + gx;
            float gi = __shfl(g, (tid & 7), 64);
            float gf = __shfl(g, (tid & 7) + 8, 64);
            float gg = __shfl(g, (tid & 7) + 16, 64);
            float go = __shfl(g, (tid & 7) + 24, 64);
            if (tid < 8) {
                float c  = cst[tid];
                float ig = 1.f / (1.f + expf(-gi));
                float fg = 1.f / (1.f + expf(-gf));
                float og = 1.f / (1.f + expf(-go));
                float cn = fg * c + ig * tanhf(gg);
                float hn = og * tanhf(cn);
                cst[tid] = cn;
                ast(&bufE[(size_t)((t + 1) % 3) * 2048 + 8 * w + tid], pack(tg + 1, hn));
            }
        }
        gx = gx_next;
        // no trailing sync: hl and red are double-buffered
    }

    // ================= latent: 3 rows per WG (h_4096 tag 4096 lives in bufE[4096%3==1]) =================
    {
        const unsigned tg = 4096u;
        const u64* p = bufE + (size_t)2048 + wv * 128 + 2 * lane;
        u64 a0 = ald(p), a1 = ald(p + 1);
        for (;;) {
            bool ok = ((unsigned)(a0 >> 32) == tg) & ((unsigned)(a1 >> 32) == tg);
            if (__builtin_expect(__all(ok), 1)) break;
            a0 = ald(p); a1 = ald(p + 1);
        }
        float2 hv = { __uint_as_float((unsigned)a0), __uint_as_float((unsigned)a1) };
        *(float2*)&hl[0][wv * 128 + 2 * lane] = hv;
        __syncthreads();

        if (wv < 3) {
            int row = 3 * w + wv;
            const float* wr = Wls + (size_t)row * 2048;
            float s = 0.f;
            #pragma unroll
            for (int q = 0; q < 32; q++) s += wr[lane + 64 * q] * hl[0][lane + 64 * q];
            for (int o = 32; o; o >>= 1) s += __shfl_xor(s, o, 64);
            if (lane == 0) {
                float lv = tanhf(s + bls[row]);
                out[128 + row] = lv;
                ast(&bufD[128 + row], pack(0u, lv));
            }
        }
        __syncthreads();   // hl[0] reads done before decoder s=1 re-stages hl[0]
    }

    // ---- decoder weights: wave wv owns row wv (gate = wv>>2, h-slot = wv&3 -> 4w + (wv&3)).
    //      Lane owns k = lane + 64*j  (16 weight floats/lane).
    const int Rd = (wv >> 2) * 1024 + 4 * w + (wv & 3);
    float wd[16];
    {
        const float* src = wsum + (size_t)Rd * 1024 + lane;
        #pragma unroll
        for (int j = 0; j < 16; j++) wd[j] = src[64 * j];
    }
    float bdv = 0.f, pgv = 0.f;
    if (tid < 16) {
        int R = (tid >> 2) * 1024 + 4 * w + (tid & 3);
        bdv = bih_d[R] + bhh_d[R];
        pgv = pg[R];
    }
    if (tid < 8) cst[tid] = 0.f;
    if (tid < 4) {   // c0 = latent_cat[4w+tid]: poll tag 0
        const u64* pc = bufD + 4 * w + tid;
        u64 v;
        do { v = ald(pc); } while ((unsigned)(v >> 32) != 0u);
        cst[tid] = __uint_as_float((unsigned)v);
    }
    __syncthreads();

    // ================= decoder: 4094 steps =================
    #pragma unroll 1
    for (int s = 1; s <= 4094; s++) {
        const unsigned tg = (unsigned)(s - 1);
        const u64* p = bufD + (size_t)((s - 1) % 3) * 1024 + wv * 64 + lane;
        u64 a0 = ald(p);
        for (;;) {
            bool ok = ((unsigned)(a0 >> 32) == tg);
            if (__builtin_expect(__all(ok), 1)) break;
            a0 = ald(p);
        }
        hl[(s - 1) & 1][wv * 64 + lane] = __uint_as_float((unsigned)a0);
        __syncthreads();

        float s0 = 0.f;
        const float* hp = hl[(s - 1) & 1];
        if (s == 1) {
            // step 1 uses W_hh_dec alone (input term for emb[X] is folded into pg)
            const float* srcw = Whh_d + (size_t)Rd * 1024 + lane;
            #pragma unroll
            for (int j = 0; j < 16; j++) s0 += srcw[64 * j] * hp[lane + 64 * j];
        } else {
            #pragma unroll
            for (int j = 0; j < 16; j++) s0 += wd[j] * hp[lane + 64 * j];
        }
        #pragma unroll
        for (int o = 32; o; o >>= 1) s0 += __shfl_xor(s0, o, 64);
        if (lane == 0) red[(s - 1) & 1][wv] = s0;
        __syncthreads();

        if (tid < 16) {
            float g = red[(s - 1) & 1][tid] + ((s == 1) ? pgv : bdv);
            float gi = __shfl(g, (tid & 3), 64);
            float gf = __shfl(g, (tid & 3) + 4, 64);
            float gg = __shfl(g, (tid & 3) + 8, 64);
            float go = __shfl(g, (tid & 3) + 12, 64);
            if (tid < 4) {
                float c  = cst[tid];
                float ig = 1.f / (1.f + expf(-gi));
                float fg = 1.f / (1.f + expf(-gf));
                float og = 1.f / (1.f + expf(-go));
                float cn = fg * c + ig * tanhf(gg);
                float hn = og * tanhf(cn);
                cst[tid] = cn;
                out[1024 + (size_t)(4095 - s) * 1024 + 4 * w + tid] = hn;
                ast(&bufD[(size_t)(s % 3) * 1024 + 4 * w + tid], pack((unsigned)s, hn));
            }
        }
        // no trailing sync: hl and red double-buffered
    }
}

// ---------------- host launcher ----------------
extern "C" void kernel_launch(void* const* d_in, const int* in_sizes, int n_in,
                              void* d_out, int out_size, void* d_ws, size_t ws_size,
                              hipStream_t stream)
{
    const int* x      = (const int*)d_in[0];
    const int* Vg     = (const int*)d_in[1];
    const int* Jg     = (const int*)d_in[2];
    const float* emb   = (const float*)d_in[4];
    const float* embV  = (const float*)d_in[5];
    const float* embJ  = (const float*)d_in[6];
    const float* Wih_e = (const float*)d_in[7];
    const float* Whh_e = (const float*)d_in[8];
    const float* bih_e = (const float*)d_in[9];
    const float* bhh_e = (const float*)d_in[10];
    const float* Wls   = (const float*)d_in[11];
    const float* bls   = (const float*)d_in[12];
    const float* Wih_d = (const float*)d_in[13];
    const float* Whh_d = (const float*)d_in[14];
    const float* bih_d = (const float*)d_in[15];
    const float* bhh_d = (const float*)d_in[16];
    float* out = (float*)d_out;

    char* ws = (char*)d_ws;
    u64*   bufE = (u64*)ws;                     // [3][2048]  -> 49152 B
    u64*   bufD = (u64*)(ws + 49152);           // [3][1024]  -> 24576 B
    float* pg   = (float*)(ws + 73728);         // [4096]     -> 16384 B
    short* Abf  = (short*)(ws + 90368);         // [4096*1024]
    short* Wbf  = (short*)(ws + 8478976);       // [8192*1024]
    float* wsum = (float*)(ws + 25256192);      // [4096*1024]
    float* Gx   = (float*)(ws + 42033408);      // [4096][8192]  (total 176,251,136 B)

    prep_all<<<1024, 256, 0, stream>>>(x, Vg, Jg, emb, embV, embJ,
                                       Wih_e, Wih_d, Whh_d,
                                       out, Abf, Wbf, wsum, bufE, bufD);
    prep_pg<<<64, 256, 0, stream>>>(Wih_d, emb, bih_d, bhh_d, pg);
    gemm_xgates<<<2048, 256, 0, stream>>>(Abf, Wbf, bih_e, bhh_e, Gx);

    void* args[] = { (void*)&Whh_e, (void*)&Wls, (void*)&bls, (void*)&Whh_d,
                     (void*)&Gx, (void*)&wsum, (void*)&bih_d, (void*)&bhh_d, (void*)&pg,
                     (void*)&bufE, (void*)&bufD, (void*)&out };
    hipLaunchCooperativeKernel((const void*)rnn_seq, dim3(NWG), dim3(1024), args, 0, stream);
}